// Round 5
// baseline (1039.211 us; speedup 1.0000x reference)
//
#include <hip/hip_runtime.h>
#include <math.h>

#define Bsz 512
#define Tsz 512
#define Fin 32
#define Hd 64
#define CHUNK 32
#define NCH (Tsz / CHUNK)

typedef float v2f __attribute__((ext_vector_type(2)));

// v_rcp_f32-based activations (no IEEE div sequence; ~1 ulp)
__device__ __forceinline__ float fsig(float x) {
    return __builtin_amdgcn_rcpf(1.0f + __expf(-x));
}
__device__ __forceinline__ float ftanh(float x) {
    return fmaf(2.0f, __builtin_amdgcn_rcpf(1.0f + __expf(-2.0f * x)), -1.0f);
}

// Pin float4 components into arch VGPRs (round-3 proven, harmless).
#define PIN4(v4) \
    asm volatile("" : "+v"((v4).x), "+v"((v4).y), "+v"((v4).z), "+v"((v4).w))

// ---------------- Layer 0: x[B,T,32] -> h1[B,T,64] ----------------
// R5: TWO batches per block. R1/R4 showed the ~1600-1900 cyc step time is a
// FIXED serial latency chain (barrier + gate-LDS round-trip + transcendental
// chains), independent of dot-product work. So amortize: one block carries
// batches 2*blk and 2*blk+1; weights (VGPR-heavy) are shared; the two
// batches' chains are register-independent -> ILP fills the latency shadows.
// Structure per batch identical to R3 (proven): LDS-staged x, one barrier
// per step, parity-double-buffered stride-5 gate buffer, per-wave private h.
__global__ __launch_bounds__(256, 1)
void lstm_layer0(const float* __restrict__ x,
                 const float4* __restrict__ Wih4,
                 const float4* __restrict__ Whh4,
                 const float* __restrict__ bih,
                 const float* __restrict__ bhh,
                 float* __restrict__ h1out)
{
    __shared__ __align__(16) float xbuf[2][2][CHUNK * Fin]; // [batch][dbuf] 16KB
    __shared__ __align__(16) float hcopy[2][4][Hd];         // [batch][wave]
    __shared__ float glds[2][2][Hd * 5];                    // [batch][parity]

    const int tid  = threadIdx.x;
    const int lane = tid & 63;
    const int wv   = tid >> 6;
    const int wvu  = __builtin_amdgcn_readfirstlane(wv);
    const int b0   = blockIdx.x * 2;
    const int b1   = b0 + 1;

    float4 wih[8];
#pragma unroll
    for (int q = 0; q < 8; ++q) wih[q] = Wih4[tid * 8 + q];
    float4 whh[16];
#pragma unroll
    for (int q = 0; q < 16; ++q) whh[q] = Whh4[tid * 16 + q];
    const float bias = bih[tid] + bhh[tid];

    float c0 = 0.0f, c1 = 0.0f;
    hcopy[0][wv][lane] = 0.0f;
    hcopy[1][wv][lane] = 0.0f;

    const float4* xs0 = (const float4*)(x + (size_t)b0 * Tsz * Fin);
    const float4* xs1 = (const float4*)(x + (size_t)b1 * Tsz * Fin);
    ((float4*)xbuf[0][0])[tid] = xs0[tid];
    ((float4*)xbuf[1][0])[tid] = xs1[tid];
    float* hout0 = h1out + (size_t)b0 * Tsz * Hd + lane;
    float* hout1 = h1out + (size_t)b1 * Tsz * Hd + lane;
    __syncthreads();

    for (int ci = 0; ci < NCH; ++ci) {
        const int cur = ci & 1;
        if (ci + 1 < NCH) {
            ((float4*)xbuf[0][cur ^ 1])[tid] = xs0[(ci + 1) * (CHUNK * Fin / 4) + tid];
            ((float4*)xbuf[1][cur ^ 1])[tid] = xs1[(ci + 1) * (CHUNK * Fin / 4) + tid];
        }
#pragma unroll
        for (int q = 0; q < 8; ++q)  PIN4(wih[q]);
#pragma unroll
        for (int q = 0; q < 16; ++q) PIN4(whh[q]);
#pragma unroll 1
        for (int ct = 0; ct < CHUNK; ct += 2) {
#pragma unroll
            for (int pp = 0; pp < 2; ++pp) {   // glds parity compile-time
                const int t = ci * CHUNK + ct + pp;
                const float4* xr0 = (const float4*)&xbuf[0][cur][(ct + pp) * Fin];
                const float4* xr1 = (const float4*)&xbuf[1][cur][(ct + pp) * Fin];
                const float4* hr0 = (const float4*)&hcopy[0][wv][0];
                const float4* hr1 = (const float4*)&hcopy[1][wv][0];

                v2f p0 = {bias, 0.0f}, p1 = {0.0f, 0.0f}; // batch0 acc
                v2f q0 = {bias, 0.0f}, q1 = {0.0f, 0.0f}; // batch1 acc
#pragma unroll
                for (int q = 0; q < 8; ++q) {
                    float4 w4 = wih[q];
                    v2f w0 = {w4.x, w4.y}, w1 = {w4.z, w4.w};
                    float4 xa = xr0[q], xb = xr1[q];
                    v2f a0 = {xa.x, xa.y}, a1 = {xa.z, xa.w};
                    v2f b0v = {xb.x, xb.y}, b1v = {xb.z, xb.w};
                    p0 = __builtin_elementwise_fma(a0, w0, p0);
                    p1 = __builtin_elementwise_fma(a1, w1, p1);
                    q0 = __builtin_elementwise_fma(b0v, w0, q0);
                    q1 = __builtin_elementwise_fma(b1v, w1, q1);
                }
#pragma unroll
                for (int q = 0; q < 16; ++q) {
                    float4 w4 = whh[q];
                    v2f w0 = {w4.x, w4.y}, w1 = {w4.z, w4.w};
                    float4 ha = hr0[q], hb = hr1[q];
                    v2f a0 = {ha.x, ha.y}, a1 = {ha.z, ha.w};
                    v2f b0v = {hb.x, hb.y}, b1v = {hb.z, hb.w};
                    p0 = __builtin_elementwise_fma(a0, w0, p0);
                    p1 = __builtin_elementwise_fma(a1, w1, p1);
                    q0 = __builtin_elementwise_fma(b0v, w0, q0);
                    q1 = __builtin_elementwise_fma(b1v, w1, q1);
                }
                float aa = (p0.x + p0.y) + (p1.x + p1.y);
                float ab = (q0.x + q0.y) + (q1.x + q1.y);
                if (wvu == 2) {
                    glds[0][pp][lane * 5 + wv] = ftanh(aa);
                    glds[1][pp][lane * 5 + wv] = ftanh(ab);
                } else {
                    glds[0][pp][lane * 5 + wv] = fsig(aa);
                    glds[1][pp][lane * 5 + wv] = fsig(ab);
                }
                __syncthreads();
                float gi0 = glds[0][pp][lane * 5 + 0];
                float gf0 = glds[0][pp][lane * 5 + 1];
                float gg0 = glds[0][pp][lane * 5 + 2];
                float go0 = glds[0][pp][lane * 5 + 3];
                float gi1 = glds[1][pp][lane * 5 + 0];
                float gf1 = glds[1][pp][lane * 5 + 1];
                float gg1 = glds[1][pp][lane * 5 + 2];
                float go1 = glds[1][pp][lane * 5 + 3];
                c0 = fmaf(gf0, c0, gi0 * gg0);
                c1 = fmaf(gf1, c1, gi1 * gg1);
                float h0 = go0 * ftanh(c0);
                float h1 = go1 * ftanh(c1);
                hcopy[0][wv][lane] = h0;
                hcopy[1][wv][lane] = h1;
                if (wvu == 0) hout0[(size_t)t * Hd] = h0;
                if (wvu == 1) hout1[(size_t)t * Hd] = h1;
            }
        }
    }
}

// ------- Layer 1 + FC: h1[B,T,64] -> out[B] -------
__global__ __launch_bounds__(256, 1)
void lstm_layer1_fc(const float* __restrict__ h1,
                    const float4* __restrict__ Wih4,
                    const float4* __restrict__ Whh4,
                    const float* __restrict__ bih,
                    const float* __restrict__ bhh,
                    const float* __restrict__ fcW,
                    const float* __restrict__ fcb,
                    float* __restrict__ out)
{
    __shared__ __align__(16) float xbuf[2][2][CHUNK * Hd]; // 32KB
    __shared__ __align__(16) float hcopy[2][4][Hd];
    __shared__ float glds[2][2][Hd * 5];

    const int tid  = threadIdx.x;
    const int lane = tid & 63;
    const int wv   = tid >> 6;
    const int wvu  = __builtin_amdgcn_readfirstlane(wv);
    const int b0   = blockIdx.x * 2;
    const int b1   = b0 + 1;

    float4 wih[16];
#pragma unroll
    for (int q = 0; q < 16; ++q) wih[q] = Wih4[tid * 16 + q];
    float4 whh[16];
#pragma unroll
    for (int q = 0; q < 16; ++q) whh[q] = Whh4[tid * 16 + q];
    const float bias = bih[tid] + bhh[tid];

    float c0 = 0.0f, c1 = 0.0f;
    float hl0 = 0.0f, hl1 = 0.0f;
    hcopy[0][wv][lane] = 0.0f;
    hcopy[1][wv][lane] = 0.0f;

    const float4* xs0 = (const float4*)(h1 + (size_t)b0 * Tsz * Hd);
    const float4* xs1 = (const float4*)(h1 + (size_t)b1 * Tsz * Hd);
    ((float4*)xbuf[0][0])[tid]       = xs0[tid];
    ((float4*)xbuf[0][0])[tid + 256] = xs0[tid + 256];
    ((float4*)xbuf[1][0])[tid]       = xs1[tid];
    ((float4*)xbuf[1][0])[tid + 256] = xs1[tid + 256];
    __syncthreads();

    for (int ci = 0; ci < NCH; ++ci) {
        const int cur = ci & 1;
        if (ci + 1 < NCH) {
            const int base = (ci + 1) * (CHUNK * Hd / 4);
            ((float4*)xbuf[0][cur ^ 1])[tid]       = xs0[base + tid];
            ((float4*)xbuf[0][cur ^ 1])[tid + 256] = xs0[base + tid + 256];
            ((float4*)xbuf[1][cur ^ 1])[tid]       = xs1[base + tid];
            ((float4*)xbuf[1][cur ^ 1])[tid + 256] = xs1[base + tid + 256];
        }
#pragma unroll
        for (int q = 0; q < 16; ++q) PIN4(wih[q]);
#pragma unroll
        for (int q = 0; q < 16; ++q) PIN4(whh[q]);
#pragma unroll 1
        for (int ct = 0; ct < CHUNK; ct += 2) {
#pragma unroll
            for (int pp = 0; pp < 2; ++pp) {
                const float4* xr0 = (const float4*)&xbuf[0][cur][(ct + pp) * Hd];
                const float4* xr1 = (const float4*)&xbuf[1][cur][(ct + pp) * Hd];
                const float4* hr0 = (const float4*)&hcopy[0][wv][0];
                const float4* hr1 = (const float4*)&hcopy[1][wv][0];

                v2f p0 = {bias, 0.0f}, p1 = {0.0f, 0.0f};
                v2f q0 = {bias, 0.0f}, q1 = {0.0f, 0.0f};
#pragma unroll
                for (int q = 0; q < 16; ++q) {
                    float4 w4 = wih[q];
                    v2f w0 = {w4.x, w4.y}, w1 = {w4.z, w4.w};
                    float4 xa = xr0[q], xb = xr1[q];
                    v2f a0 = {xa.x, xa.y}, a1 = {xa.z, xa.w};
                    v2f b0v = {xb.x, xb.y}, b1v = {xb.z, xb.w};
                    p0 = __builtin_elementwise_fma(a0, w0, p0);
                    p1 = __builtin_elementwise_fma(a1, w1, p1);
                    q0 = __builtin_elementwise_fma(b0v, w0, q0);
                    q1 = __builtin_elementwise_fma(b1v, w1, q1);
                }
#pragma unroll
                for (int q = 0; q < 16; ++q) {
                    float4 w4 = whh[q];
                    v2f w0 = {w4.x, w4.y}, w1 = {w4.z, w4.w};
                    float4 ha = hr0[q], hb = hr1[q];
                    v2f a0 = {ha.x, ha.y}, a1 = {ha.z, ha.w};
                    v2f b0v = {hb.x, hb.y}, b1v = {hb.z, hb.w};
                    p0 = __builtin_elementwise_fma(a0, w0, p0);
                    p1 = __builtin_elementwise_fma(a1, w1, p1);
                    q0 = __builtin_elementwise_fma(b0v, w0, q0);
                    q1 = __builtin_elementwise_fma(b1v, w1, q1);
                }
                float aa = (p0.x + p0.y) + (p1.x + p1.y);
                float ab = (q0.x + q0.y) + (q1.x + q1.y);
                if (wvu == 2) {
                    glds[0][pp][lane * 5 + wv] = ftanh(aa);
                    glds[1][pp][lane * 5 + wv] = ftanh(ab);
                } else {
                    glds[0][pp][lane * 5 + wv] = fsig(aa);
                    glds[1][pp][lane * 5 + wv] = fsig(ab);
                }
                __syncthreads();
                float gi0 = glds[0][pp][lane * 5 + 0];
                float gf0 = glds[0][pp][lane * 5 + 1];
                float gg0 = glds[0][pp][lane * 5 + 2];
                float go0 = glds[0][pp][lane * 5 + 3];
                float gi1 = glds[1][pp][lane * 5 + 0];
                float gf1 = glds[1][pp][lane * 5 + 1];
                float gg1 = glds[1][pp][lane * 5 + 2];
                float go1 = glds[1][pp][lane * 5 + 3];
                c0  = fmaf(gf0, c0, gi0 * gg0);
                c1  = fmaf(gf1, c1, gi1 * gg1);
                hl0 = go0 * ftanh(c0);
                hl1 = go1 * ftanh(c1);
                hcopy[0][wv][lane] = hl0;
                hcopy[1][wv][lane] = hl1;
            }
        }
    }
    // fused FC on last h2: wave 0 -> batch0, wave 1 -> batch1 (hl replicated)
    if (wvu == 0) {
        float psum = hl0 * fcW[lane];
#pragma unroll
        for (int off = 32; off > 0; off >>= 1)
            psum += __shfl_down(psum, off);
        if (lane == 0) out[b0] = psum + fcb[0];
    }
    if (wvu == 1) {
        float psum = hl1 * fcW[lane];
#pragma unroll
        for (int off = 32; off > 0; off >>= 1)
            psum += __shfl_down(psum, off);
        if (lane == 0) out[b1] = psum + fcb[0];
    }
}

extern "C" void kernel_launch(void* const* d_in, const int* in_sizes, int n_in,
                              void* d_out, int out_size, void* d_ws, size_t ws_size,
                              hipStream_t stream)
{
    const float* x    = (const float*)d_in[0];
    const float* Wih0 = (const float*)d_in[1];
    const float* Whh0 = (const float*)d_in[2];
    const float* bih0 = (const float*)d_in[3];
    const float* bhh0 = (const float*)d_in[4];
    const float* Wih1 = (const float*)d_in[5];
    const float* Whh1 = (const float*)d_in[6];
    const float* bih1 = (const float*)d_in[7];
    const float* bhh1 = (const float*)d_in[8];
    const float* fcW  = (const float*)d_in[9];
    const float* fcb  = (const float*)d_in[10];
    float* out = (float*)d_out;
    float* h1  = (float*)d_ws; // B*T*H fp32 = 64 MB scratch

    lstm_layer0<<<dim3(Bsz / 2), dim3(256), 0, stream>>>(
        x, (const float4*)Wih0, (const float4*)Whh0, bih0, bhh0, h1);
    lstm_layer1_fc<<<dim3(Bsz / 2), dim3(256), 0, stream>>>(
        h1, (const float4*)Wih1, (const float4*)Whh1, bih1, bhh1, fcW, fcb, out);
}

// Round 6
// 945.678 us; speedup vs baseline: 1.0989x; 1.0989x over previous
//
#include <hip/hip_runtime.h>
#include <math.h>

#define Bsz 512
#define Tsz 512
#define Fin 32
#define Hd 64
#define CHUNK 32
#define NCH (Tsz / CHUNK)

typedef float v2f __attribute__((ext_vector_type(2)));

// v_rcp_f32-based activations (no IEEE div sequence; ~1 ulp)
__device__ __forceinline__ float fsig(float x) {
    return __builtin_amdgcn_rcpf(1.0f + __expf(-x));
}
__device__ __forceinline__ float ftanh(float x) {
    return fmaf(2.0f, __builtin_amdgcn_rcpf(1.0f + __expf(-2.0f * x)), -1.0f);
}
// Wave-register broadcast: h[k] lives in lane k's hreg (every thread computes
// h for dim=lane redundantly). readlane is pure VALU - no LDS return traffic,
// which rounds 0-5 indicate is the shared bottleneck (uniform ds_read_b128
// still pays 64 lanes x 16B through the LDS return path).
__device__ __forceinline__ float bcast(float v, int k) {
    return __int_as_float(__builtin_amdgcn_readlane(__float_as_int(v), k));
}

// Pin float4 components into arch VGPRs (blocks AGPR parking; round-3 proven).
#define PIN4(v4) \
    asm volatile("" : "+v"((v4).x), "+v"((v4).y), "+v"((v4).z), "+v"((v4).w))

// ---------------- Layer 0: x[B,T,32] -> h1[B,T,64] ----------------
// R6: back to R3's proven shell (grid 512, 256 thr, 2 blocks/CU for phase
// overlap), but the h-recurrence no longer touches LDS: h stays distributed
// in wave registers (lane k holds h[k]); the h-dot is 64x {readlane + fmac}.
// Removes the hcopy write->read round trip from the serial chain and 16 of
// the per-step broadcast b128 LDS reads. Gates still cross waves via the
// parity-double-buffered stride-5 glds (conflict-free), one barrier/step.
__global__ __launch_bounds__(256, 2)
void lstm_layer0(const float* __restrict__ x,
                 const float4* __restrict__ Wih4,
                 const float4* __restrict__ Whh4,
                 const float* __restrict__ bih,
                 const float* __restrict__ bhh,
                 float* __restrict__ h1out)
{
    __shared__ __align__(16) float xbuf[2][CHUNK * Fin]; // 2 x 4KB
    __shared__ float glds[2][Hd * 5];                    // gates, stride 5

    const int tid  = threadIdx.x;
    const int lane = tid & 63;
    const int wv   = tid >> 6;
    const int wvu  = __builtin_amdgcn_readfirstlane(wv);
    const int b    = blockIdx.x;

    float4 wih[8];
#pragma unroll
    for (int q = 0; q < 8; ++q) wih[q] = Wih4[tid * 8 + q];
    float4 whh[16];
#pragma unroll
    for (int q = 0; q < 16; ++q) whh[q] = Whh4[tid * 16 + q];
    const float bias = bih[tid] + bhh[tid];

    float c = 0.0f, hreg = 0.0f;

    const float4* xsrc = (const float4*)(x + (size_t)b * Tsz * Fin);
    ((float4*)xbuf[0])[tid] = xsrc[tid];
    float* hout = h1out + (size_t)b * Tsz * Hd + lane;
    __syncthreads();

    for (int ci = 0; ci < NCH; ++ci) {
        const int cur = ci & 1;
        if (ci + 1 < NCH)
            ((float4*)xbuf[cur ^ 1])[tid] = xsrc[(ci + 1) * (CHUNK * Fin / 4) + tid];
#pragma unroll
        for (int q = 0; q < 8; ++q)  PIN4(wih[q]);
#pragma unroll
        for (int q = 0; q < 16; ++q) PIN4(whh[q]);
#pragma unroll 1
        for (int ct = 0; ct < CHUNK; ct += 2) {
#pragma unroll
            for (int pp = 0; pp < 2; ++pp) {   // glds parity compile-time
                const int t = ci * CHUNK + ct + pp;
                // x-dot from LDS (broadcast reads; off the critical path)
                const float4* xrow = (const float4*)&xbuf[cur][(ct + pp) * Fin];
                v2f a0 = {bias, 0.0f}, a1 = {0.0f, 0.0f};
#pragma unroll
                for (int q = 0; q < 8; ++q) {
                    float4 xv = xrow[q];
                    v2f b0 = {xv.x, xv.y}, b1 = {xv.z, xv.w};
                    v2f w0 = {wih[q].x, wih[q].y}, w1 = {wih[q].z, wih[q].w};
                    a0 = __builtin_elementwise_fma(b0, w0, a0);
                    a1 = __builtin_elementwise_fma(b1, w1, a1);
                }
                float ax = (a0.x + a0.y) + (a1.x + a1.y);
                // h-dot from wave registers: 64x readlane+fmac, 4 chains
                const float* wf = (const float*)whh;
                float h0 = ax, h1 = 0.0f, h2 = 0.0f, h3 = 0.0f;
#pragma unroll
                for (int k = 0; k < 64; k += 4) {
                    h0 = fmaf(bcast(hreg, k + 0), wf[k + 0], h0);
                    h1 = fmaf(bcast(hreg, k + 1), wf[k + 1], h1);
                    h2 = fmaf(bcast(hreg, k + 2), wf[k + 2], h2);
                    h3 = fmaf(bcast(hreg, k + 3), wf[k + 3], h3);
                }
                float a = (h0 + h1) + (h2 + h3);
                if (wvu == 2) glds[pp][lane * 5 + wv] = ftanh(a);
                else          glds[pp][lane * 5 + wv] = fsig(a);
                __syncthreads();
                float gi = glds[pp][lane * 5 + 0];
                float gf = glds[pp][lane * 5 + 1];
                float gg = glds[pp][lane * 5 + 2];
                float go = glds[pp][lane * 5 + 3];
                c = fmaf(gf, c, gi * gg);
                hreg = go * ftanh(c);
                if (wvu == 0) hout[(size_t)t * Hd] = hreg;
            }
        }
    }
}

// ------- Layer 1 + FC: h1[B,T,64] -> out[B] -------
__global__ __launch_bounds__(256, 2)
void lstm_layer1_fc(const float* __restrict__ h1,
                    const float4* __restrict__ Wih4,
                    const float4* __restrict__ Whh4,
                    const float* __restrict__ bih,
                    const float* __restrict__ bhh,
                    const float* __restrict__ fcW,
                    const float* __restrict__ fcb,
                    float* __restrict__ out)
{
    __shared__ __align__(16) float xbuf[2][CHUNK * Hd]; // 2 x 8KB
    __shared__ float glds[2][Hd * 5];

    const int tid  = threadIdx.x;
    const int lane = tid & 63;
    const int wv   = tid >> 6;
    const int wvu  = __builtin_amdgcn_readfirstlane(wv);
    const int b    = blockIdx.x;

    float4 wih[16];
#pragma unroll
    for (int q = 0; q < 16; ++q) wih[q] = Wih4[tid * 16 + q];
    float4 whh[16];
#pragma unroll
    for (int q = 0; q < 16; ++q) whh[q] = Whh4[tid * 16 + q];
    const float bias = bih[tid] + bhh[tid];

    float c = 0.0f, hreg = 0.0f;

    const float4* xsrc = (const float4*)(h1 + (size_t)b * Tsz * Hd);
    ((float4*)xbuf[0])[tid]       = xsrc[tid];
    ((float4*)xbuf[0])[tid + 256] = xsrc[tid + 256];
    __syncthreads();

    for (int ci = 0; ci < NCH; ++ci) {
        const int cur = ci & 1;
        if (ci + 1 < NCH) {
            ((float4*)xbuf[cur ^ 1])[tid]       = xsrc[(ci + 1) * (CHUNK * Hd / 4) + tid];
            ((float4*)xbuf[cur ^ 1])[tid + 256] = xsrc[(ci + 1) * (CHUNK * Hd / 4) + tid + 256];
        }
#pragma unroll
        for (int q = 0; q < 16; ++q) PIN4(wih[q]);
#pragma unroll
        for (int q = 0; q < 16; ++q) PIN4(whh[q]);
#pragma unroll 1
        for (int ct = 0; ct < CHUNK; ct += 2) {
#pragma unroll
            for (int pp = 0; pp < 2; ++pp) {
                const float4* xrow = (const float4*)&xbuf[cur][(ct + pp) * Hd];
                v2f a0 = {bias, 0.0f}, a1 = {0.0f, 0.0f};
#pragma unroll
                for (int q = 0; q < 16; ++q) {
                    float4 xv = xrow[q];
                    v2f b0 = {xv.x, xv.y}, b1 = {xv.z, xv.w};
                    v2f w0 = {wih[q].x, wih[q].y}, w1 = {wih[q].z, wih[q].w};
                    a0 = __builtin_elementwise_fma(b0, w0, a0);
                    a1 = __builtin_elementwise_fma(b1, w1, a1);
                }
                float ax = (a0.x + a0.y) + (a1.x + a1.y);
                const float* wf = (const float*)whh;
                float h0 = ax, h1 = 0.0f, h2 = 0.0f, h3 = 0.0f;
#pragma unroll
                for (int k = 0; k < 64; k += 4) {
                    h0 = fmaf(bcast(hreg, k + 0), wf[k + 0], h0);
                    h1 = fmaf(bcast(hreg, k + 1), wf[k + 1], h1);
                    h2 = fmaf(bcast(hreg, k + 2), wf[k + 2], h2);
                    h3 = fmaf(bcast(hreg, k + 3), wf[k + 3], h3);
                }
                float a = (h0 + h1) + (h2 + h3);
                if (wvu == 2) glds[pp][lane * 5 + wv] = ftanh(a);
                else          glds[pp][lane * 5 + wv] = fsig(a);
                __syncthreads();
                float gi = glds[pp][lane * 5 + 0];
                float gf = glds[pp][lane * 5 + 1];
                float gg = glds[pp][lane * 5 + 2];
                float go = glds[pp][lane * 5 + 3];
                c    = fmaf(gf, c, gi * gg);
                hreg = go * ftanh(c);
            }
        }
    }
    // fused FC on last h2 (wave 0 only; hreg holds h2[b, T-1, lane])
    if (wvu == 0) {
        float psum = hreg * fcW[lane];
#pragma unroll
        for (int off = 32; off > 0; off >>= 1)
            psum += __shfl_down(psum, off);
        if (lane == 0) out[b] = psum + fcb[0];
    }
}

extern "C" void kernel_launch(void* const* d_in, const int* in_sizes, int n_in,
                              void* d_out, int out_size, void* d_ws, size_t ws_size,
                              hipStream_t stream)
{
    const float* x    = (const float*)d_in[0];
    const float* Wih0 = (const float*)d_in[1];
    const float* Whh0 = (const float*)d_in[2];
    const float* bih0 = (const float*)d_in[3];
    const float* bhh0 = (const float*)d_in[4];
    const float* Wih1 = (const float*)d_in[5];
    const float* Whh1 = (const float*)d_in[6];
    const float* bih1 = (const float*)d_in[7];
    const float* bhh1 = (const float*)d_in[8];
    const float* fcW  = (const float*)d_in[9];
    const float* fcb  = (const float*)d_in[10];
    float* out = (float*)d_out;
    float* h1  = (float*)d_ws; // B*T*H fp32 = 64 MB scratch

    lstm_layer0<<<dim3(Bsz), dim3(256), 0, stream>>>(
        x, (const float4*)Wih0, (const float4*)Whh0, bih0, bhh0, h1);
    lstm_layer1_fc<<<dim3(Bsz), dim3(256), 0, stream>>>(
        h1, (const float4*)Wih1, (const float4*)Whh1, bih1, bhh1, fcW, fcb, out);
}

// Round 7
// 827.554 us; speedup vs baseline: 1.2558x; 1.1427x over previous
//
#include <hip/hip_runtime.h>
#include <math.h>

#define Bsz 512
#define Tsz 512
#define Fin 32
#define Hd 64
#define CHUNK 32
#define NCH (Tsz / CHUNK)

typedef float v2f __attribute__((ext_vector_type(2)));

// v_rcp_f32-based activations (no IEEE div sequence; ~1 ulp)
__device__ __forceinline__ float fsig(float x) {
    return __builtin_amdgcn_rcpf(1.0f + __expf(-x));
}
__device__ __forceinline__ float ftanh(float x) {
    return fmaf(2.0f, __builtin_amdgcn_rcpf(1.0f + __expf(-2.0f * x)), -1.0f);
}

// Pin float4 components into arch VGPRs (blocks AGPR parking; round-3 proven).
#define PIN4(v4) \
    asm volatile("" : "+v"((v4).x), "+v"((v4).y), "+v"((v4).z), "+v"((v4).w))

// ---------------- Layer 0: x[B,T,32] -> h1[B,T,64] ----------------
// R7 layout: thread tid owns gate q=tid&3 of h-dim d=tid>>2. The 4 gates of
// a dim sit in 4 ADJACENT LANES of one wave -> combined with a 3-shuffle quad
// butterfly (no LDS, no barrier) instead of R3's gate-LDS write->read round
// trip. Each quad redundantly computes c,h; quad leader writes the single
// hrow[64] h-vector (parity double-buffered; replaces glds AND hcopy).
// Activation is branchless-unified: act = fmaf(k, sigmoid(k*a), b) with
// per-lane (k,b) = (2,-1) for tanh-gate else (1,0). One barrier per step;
// the x-dot for t+1 is computed in the barrier shadow (from LDS - R4 showed
// global-sourced x is a regression). Grid 512, 2 blocks/CU phase overlap.
__global__ __launch_bounds__(256, 2)
void lstm_layer0(const float* __restrict__ x,
                 const float4* __restrict__ Wih4,
                 const float4* __restrict__ Whh4,
                 const float* __restrict__ bih,
                 const float* __restrict__ bhh,
                 float* __restrict__ h1out)
{
    __shared__ __align__(16) float xbuf[2][CHUNK * Fin]; // 2 x 4KB
    __shared__ __align__(16) float hrow[2][Hd];          // 512B

    const int tid = threadIdx.x;
    const int q   = tid & 3;        // 0=i 1=f 2=g(tanh) 3=o
    const int d   = tid >> 2;       // h-dim 0..63
    const int b   = blockIdx.x;
    const int r   = q * Hd + d;     // PyTorch gate-row

    float4 wih[8];
#pragma unroll
    for (int k = 0; k < 8; ++k) wih[k] = Wih4[r * 8 + k];
    float4 whh[16];
#pragma unroll
    for (int k = 0; k < 16; ++k) whh[k] = Whh4[r * 16 + k];
    const float bias = bih[r] + bhh[r];
    const float kq = (q == 2) ? 2.0f : 1.0f;
    const float bq = (q == 2) ? -1.0f : 0.0f;

    float c = 0.0f;

    const float4* xsrc = (const float4*)(x + (size_t)b * Tsz * Fin);
    ((float4*)xbuf[0])[tid] = xsrc[tid];
    if (tid < Hd) hrow[0][tid] = 0.0f;
    float* hout = h1out + (size_t)b * Tsz * Hd;
    __syncthreads();

    // x-dot for t=0
    float ax;
    {
        const float4* xr = (const float4*)&xbuf[0][0];
        v2f a0 = {bias, 0.0f}, a1 = {0.0f, 0.0f};
#pragma unroll
        for (int k = 0; k < 8; ++k) {
            float4 xv = xr[k];
            v2f b0 = {xv.x, xv.y}, b1 = {xv.z, xv.w};
            v2f w0 = {wih[k].x, wih[k].y}, w1 = {wih[k].z, wih[k].w};
            a0 = __builtin_elementwise_fma(b0, w0, a0);
            a1 = __builtin_elementwise_fma(b1, w1, a1);
        }
        ax = (a0.x + a0.y) + (a1.x + a1.y);
    }

    for (int ci = 0; ci < NCH; ++ci) {
        const int cur = ci & 1;
        if (ci + 1 < NCH)
            ((float4*)xbuf[cur ^ 1])[tid] = xsrc[(ci + 1) * (CHUNK * Fin / 4) + tid];
#pragma unroll
        for (int k = 0; k < 8; ++k)  PIN4(wih[k]);
#pragma unroll
        for (int k = 0; k < 16; ++k) PIN4(whh[k]);
#pragma unroll 1
        for (int ct = 0; ct < CHUNK; ++ct) {
            const int t = ci * CHUNK + ct;
            // h-dot on top of prefetched ax (hrow broadcast b128 reads)
            const float4* hp = (const float4*)&hrow[t & 1][0];
            v2f a0 = {ax, 0.0f}, a1 = {0.0f, 0.0f};
#pragma unroll
            for (int k = 0; k < 16; ++k) {
                float4 hv = hp[k];
                v2f b0 = {hv.x, hv.y}, b1 = {hv.z, hv.w};
                v2f w0 = {whh[k].x, whh[k].y}, w1 = {whh[k].z, whh[k].w};
                a0 = __builtin_elementwise_fma(b0, w0, a0);
                a1 = __builtin_elementwise_fma(b1, w1, a1);
            }
            float a = (a0.x + a0.y) + (a1.x + a1.y);
            // unified branchless activation
            float s   = fsig(kq * a);
            float act = fmaf(kq, s, bq);
            // quad butterfly: all 4 gates into every lane of the quad
            float x1 = __shfl_xor(act, 1);
            float la = (q & 1) ? x1 : act;   // even slot of pair: i | g
            float lb = (q & 1) ? act : x1;   // odd  slot of pair: f | o
            float ra = __shfl_xor(la, 2);
            float rb = __shfl_xor(lb, 2);
            float gi = (q & 2) ? ra : la;
            float gf = (q & 2) ? rb : lb;
            float gg = (q & 2) ? la : ra;
            float go = (q & 2) ? lb : rb;
            c = fmaf(gf, c, gi * gg);
            float h = go * ftanh(c);
            if (q == 0) {
                hrow[(t + 1) & 1][d] = h;
                hout[(size_t)t * Hd + d] = h;
            }
            // x-dot for t+1 in the barrier shadow (stale read on final iter is unused)
            {
                const float* xbase = (ct == CHUNK - 1) ? &xbuf[cur ^ 1][0]
                                                       : &xbuf[cur][(ct + 1) * Fin];
                const float4* xr = (const float4*)xbase;
                v2f a0x = {bias, 0.0f}, a1x = {0.0f, 0.0f};
#pragma unroll
                for (int k = 0; k < 8; ++k) {
                    float4 xv = xr[k];
                    v2f b0 = {xv.x, xv.y}, b1 = {xv.z, xv.w};
                    v2f w0 = {wih[k].x, wih[k].y}, w1 = {wih[k].z, wih[k].w};
                    a0x = __builtin_elementwise_fma(b0, w0, a0x);
                    a1x = __builtin_elementwise_fma(b1, w1, a1x);
                }
                ax = (a0x.x + a0x.y) + (a1x.x + a1x.y);
            }
            __syncthreads();
        }
    }
}

// ------- Layer 1 + FC: h1[B,T,64] -> out[B] -------
__global__ __launch_bounds__(256, 2)
void lstm_layer1_fc(const float* __restrict__ h1,
                    const float4* __restrict__ Wih4,
                    const float4* __restrict__ Whh4,
                    const float* __restrict__ bih,
                    const float* __restrict__ bhh,
                    const float* __restrict__ fcW,
                    const float* __restrict__ fcb,
                    float* __restrict__ out)
{
    __shared__ __align__(16) float xbuf[2][CHUNK * Hd]; // 2 x 8KB
    __shared__ __align__(16) float hrow[2][Hd];

    const int tid = threadIdx.x;
    const int q   = tid & 3;
    const int d   = tid >> 2;
    const int b   = blockIdx.x;
    const int r   = q * Hd + d;

    float4 wih[16];
#pragma unroll
    for (int k = 0; k < 16; ++k) wih[k] = Wih4[r * 16 + k];
    float4 whh[16];
#pragma unroll
    for (int k = 0; k < 16; ++k) whh[k] = Whh4[r * 16 + k];
    const float bias = bih[r] + bhh[r];
    const float kq = (q == 2) ? 2.0f : 1.0f;
    const float bq = (q == 2) ? -1.0f : 0.0f;

    float c = 0.0f;

    const float4* xsrc = (const float4*)(h1 + (size_t)b * Tsz * Hd);
    ((float4*)xbuf[0])[tid]       = xsrc[tid];
    ((float4*)xbuf[0])[tid + 256] = xsrc[tid + 256];
    if (tid < Hd) hrow[0][tid] = 0.0f;
    __syncthreads();

    float ax;
    {
        const float4* xr = (const float4*)&xbuf[0][0];
        v2f a0 = {bias, 0.0f}, a1 = {0.0f, 0.0f};
#pragma unroll
        for (int k = 0; k < 16; ++k) {
            float4 xv = xr[k];
            v2f b0 = {xv.x, xv.y}, b1 = {xv.z, xv.w};
            v2f w0 = {wih[k].x, wih[k].y}, w1 = {wih[k].z, wih[k].w};
            a0 = __builtin_elementwise_fma(b0, w0, a0);
            a1 = __builtin_elementwise_fma(b1, w1, a1);
        }
        ax = (a0.x + a0.y) + (a1.x + a1.y);
    }

    for (int ci = 0; ci < NCH; ++ci) {
        const int cur = ci & 1;
        if (ci + 1 < NCH) {
            const int base = (ci + 1) * (CHUNK * Hd / 4);
            ((float4*)xbuf[cur ^ 1])[tid]       = xsrc[base + tid];
            ((float4*)xbuf[cur ^ 1])[tid + 256] = xsrc[base + tid + 256];
        }
#pragma unroll
        for (int k = 0; k < 16; ++k) PIN4(wih[k]);
#pragma unroll
        for (int k = 0; k < 16; ++k) PIN4(whh[k]);
#pragma unroll 1
        for (int ct = 0; ct < CHUNK; ++ct) {
            const int t = ci * CHUNK + ct;
            const float4* hp = (const float4*)&hrow[t & 1][0];
            v2f a0 = {ax, 0.0f}, a1 = {0.0f, 0.0f};
#pragma unroll
            for (int k = 0; k < 16; ++k) {
                float4 hv = hp[k];
                v2f b0 = {hv.x, hv.y}, b1 = {hv.z, hv.w};
                v2f w0 = {whh[k].x, whh[k].y}, w1 = {whh[k].z, whh[k].w};
                a0 = __builtin_elementwise_fma(b0, w0, a0);
                a1 = __builtin_elementwise_fma(b1, w1, a1);
            }
            float a = (a0.x + a0.y) + (a1.x + a1.y);
            float s   = fsig(kq * a);
            float act = fmaf(kq, s, bq);
            float x1 = __shfl_xor(act, 1);
            float la = (q & 1) ? x1 : act;
            float lb = (q & 1) ? act : x1;
            float ra = __shfl_xor(la, 2);
            float rb = __shfl_xor(lb, 2);
            float gi = (q & 2) ? ra : la;
            float gf = (q & 2) ? rb : lb;
            float gg = (q & 2) ? la : ra;
            float go = (q & 2) ? lb : rb;
            c = fmaf(gf, c, gi * gg);
            float h = go * ftanh(c);
            if (q == 0) hrow[(t + 1) & 1][d] = h;
            // x-dot for t+1 in the barrier shadow
            {
                const float* xbase = (ct == CHUNK - 1) ? &xbuf[cur ^ 1][0]
                                                       : &xbuf[cur][(ct + 1) * Hd];
                const float4* xr = (const float4*)xbase;
                v2f a0x = {bias, 0.0f}, a1x = {0.0f, 0.0f};
#pragma unroll
                for (int k = 0; k < 16; ++k) {
                    float4 xv = xr[k];
                    v2f b0 = {xv.x, xv.y}, b1 = {xv.z, xv.w};
                    v2f w0 = {wih[k].x, wih[k].y}, w1 = {wih[k].z, wih[k].w};
                    a0x = __builtin_elementwise_fma(b0, w0, a0x);
                    a1x = __builtin_elementwise_fma(b1, w1, a1x);
                }
                ax = (a0x.x + a0x.y) + (a1x.x + a1x.y);
            }
            __syncthreads();
        }
    }
    // fused FC: h2[T-1] sits in hrow[0] (t=511 wrote parity 0; barrier done)
    if (tid < 64) {
        float psum = hrow[0][tid] * fcW[tid];
#pragma unroll
        for (int off = 32; off > 0; off >>= 1)
            psum += __shfl_down(psum, off);
        if (tid == 0) out[b] = psum + fcb[0];
    }
}

extern "C" void kernel_launch(void* const* d_in, const int* in_sizes, int n_in,
                              void* d_out, int out_size, void* d_ws, size_t ws_size,
                              hipStream_t stream)
{
    const float* x    = (const float*)d_in[0];
    const float* Wih0 = (const float*)d_in[1];
    const float* Whh0 = (const float*)d_in[2];
    const float* bih0 = (const float*)d_in[3];
    const float* bhh0 = (const float*)d_in[4];
    const float* Wih1 = (const float*)d_in[5];
    const float* Whh1 = (const float*)d_in[6];
    const float* bih1 = (const float*)d_in[7];
    const float* bhh1 = (const float*)d_in[8];
    const float* fcW  = (const float*)d_in[9];
    const float* fcb  = (const float*)d_in[10];
    float* out = (float*)d_out;
    float* h1  = (float*)d_ws; // B*T*H fp32 = 64 MB scratch

    lstm_layer0<<<dim3(Bsz), dim3(256), 0, stream>>>(
        x, (const float4*)Wih0, (const float4*)Whh0, bih0, bhh0, h1);
    lstm_layer1_fc<<<dim3(Bsz), dim3(256), 0, stream>>>(
        h1, (const float4*)Wih1, (const float4*)Whh1, bih1, bhh1, fcW, fcb, out);
}

// Round 8
// 743.392 us; speedup vs baseline: 1.3979x; 1.1132x over previous
//
#include <hip/hip_runtime.h>
#include <math.h>

#define Bsz 512
#define Tsz 512
#define Fin 32
#define Hd 64
#define CHUNK 32
#define NCH (Tsz / CHUNK)
#define NG 256           // 4*Hd gate rows
#define NBT (Bsz * Tsz)  // 262144 (b,t) rows

typedef float v2f __attribute__((ext_vector_type(2)));

__device__ __forceinline__ float fsig(float x) {
    return __builtin_amdgcn_rcpf(1.0f + __expf(-x));
}
__device__ __forceinline__ float ftanh(float x) {
    return fmaf(2.0f, __builtin_amdgcn_rcpf(1.0f + __expf(-2.0f * x)), -1.0f);
}

// Pin float4 components into arch VGPRs (blocks AGPR parking; round-3 proven).
#define PIN4(v4) \
    asm volatile("" : "+v"((v4).x), "+v"((v4).y), "+v"((v4).z), "+v"((v4).w))

// ============================================================================
// NEW PATH (R8): barrier-free wave-per-row recurrence + hoisted xg GEMM.
// ============================================================================

// xg[row][r] = bih[r]+bhh[r] + dot(X[row][:K], W[r][:K]); row = b*Tsz+t.
// Thread r keeps W row in VGPRs; X rows staged in LDS, broadcast-read.
template <int K>
__global__ __launch_bounds__(256, 2)
void xg_gemm(const float* __restrict__ X,
             const float4* __restrict__ W4,
             const float* __restrict__ bih,
             const float* __restrict__ bhh,
             float* __restrict__ xg)
{
    __shared__ __align__(16) float xs[64 * K];
    const int r    = threadIdx.x;
    const int row0 = blockIdx.x * 64;

    float4 w[K / 4];
#pragma unroll
    for (int j = 0; j < K / 4; ++j) w[j] = W4[r * (K / 4) + j];
    const float bias = bih[r] + bhh[r];

    const float4* xsrc = (const float4*)(X + (size_t)row0 * K);
#pragma unroll
    for (int i = 0; i < (64 * K / 4) / 256; ++i)
        ((float4*)xs)[i * 256 + r] = xsrc[i * 256 + r];
    __syncthreads();

    float* dst = xg + (size_t)row0 * NG + r;
#pragma unroll 1
    for (int j = 0; j < 64; ++j) {
        const float4* xp = (const float4*)&xs[j * K];
        v2f a0 = {bias, 0.0f}, a1 = {0.0f, 0.0f};
#pragma unroll
        for (int k = 0; k < K / 4; ++k) {
            float4 xv = xp[k];
            v2f b0 = {xv.x, xv.y}, b1 = {xv.z, xv.w};
            v2f w0 = {w[k].x, w[k].y}, w1 = {w[k].z, w[k].w};
            a0 = __builtin_elementwise_fma(b0, w0, a0);
            a1 = __builtin_elementwise_fma(b1, w1, a1);
        }
        dst[(size_t)j * NG] = (a0.x + a0.y) + (a1.x + a1.y);
    }
}

// One step of the barrier-free recurrence. Consumes prefetched gate inputs
// G0..G3 (accs init'ed with them = earliest consume), immediately re-issues
// their loads for t+2 (distance-2 prefetch covers HBM ~900cyc), h-dot from
// wave-private hrow broadcast (in-order DS pipe: no barrier needed — single
// wave, writes/reads execute in program order).
#define REC_STEP(T, G0, G1, G2, G3, DO_STORE)                                 \
    {                                                                         \
        v2f a00 = {G0, 0.f}, a01 = {0.f, 0.f};                                \
        v2f a10 = {G1, 0.f}, a11 = {0.f, 0.f};                                \
        v2f a20 = {G2, 0.f}, a21 = {0.f, 0.f};                                \
        v2f a30 = {G3, 0.f}, a31 = {0.f, 0.f};                                \
        const int tpf = ((T) + 2 < Tsz) ? (T) + 2 : (Tsz - 1);                \
        G0 = xgl[tpf * NG + 0];                                               \
        G1 = xgl[tpf * NG + 64];                                              \
        G2 = xgl[tpf * NG + 128];                                             \
        G3 = xgl[tpf * NG + 192];                                             \
        const float4* hv4 = (const float4*)hrow;                              \
        _Pragma("unroll")                                                     \
        for (int k = 0; k < 16; ++k) {                                        \
            float4 hv = hv4[k];                                               \
            v2f hb0 = {hv.x, hv.y}, hb1 = {hv.z, hv.w};                       \
            v2f w00 = {whh[0][k].x, whh[0][k].y};                             \
            v2f w01 = {whh[0][k].z, whh[0][k].w};                             \
            v2f w10 = {whh[1][k].x, whh[1][k].y};                             \
            v2f w11 = {whh[1][k].z, whh[1][k].w};                             \
            v2f w20 = {whh[2][k].x, whh[2][k].y};                             \
            v2f w21 = {whh[2][k].z, whh[2][k].w};                             \
            v2f w30 = {whh[3][k].x, whh[3][k].y};                             \
            v2f w31 = {whh[3][k].z, whh[3][k].w};                             \
            a00 = __builtin_elementwise_fma(hb0, w00, a00);                   \
            a01 = __builtin_elementwise_fma(hb1, w01, a01);                   \
            a10 = __builtin_elementwise_fma(hb0, w10, a10);                   \
            a11 = __builtin_elementwise_fma(hb1, w11, a11);                   \
            a20 = __builtin_elementwise_fma(hb0, w20, a20);                   \
            a21 = __builtin_elementwise_fma(hb1, w21, a21);                   \
            a30 = __builtin_elementwise_fma(hb0, w30, a30);                   \
            a31 = __builtin_elementwise_fma(hb1, w31, a31);                   \
        }                                                                     \
        float ai = (a00.x + a00.y) + (a01.x + a01.y);                         \
        float af = (a10.x + a10.y) + (a11.x + a11.y);                         \
        float ag = (a20.x + a20.y) + (a21.x + a21.y);                         \
        float ao = (a30.x + a30.y) + (a31.x + a31.y);                         \
        float gi = fsig(ai), gf = fsig(af);                                   \
        float gg = ftanh(ag), go = fsig(ao);                                  \
        c        = fmaf(gf, c, gi * gg);                                      \
        hcur     = go * ftanh(c);                                             \
        hrow[l]  = hcur;                                                      \
        DO_STORE;                                                             \
    }

// Layer-0 recurrence: 1 wave per batch row, zero barriers in the loop.
// Lane l owns dim l: all 4 gate rows Whh[q*64+l][:] in VGPR (256 regs;
// legal at 1 wave/SIMD - gfx950 caps at 512, no spill through ~450).
__global__ __launch_bounds__(64, 1)
void lstm_rec0(const float4* __restrict__ Whh4,
               const float* __restrict__ xg,
               float* __restrict__ h1out)
{
    __shared__ __align__(16) float hrow[Hd];
    const int l = threadIdx.x;
    const int b = blockIdx.x;

    float4 whh[4][16];
#pragma unroll
    for (int q = 0; q < 4; ++q)
#pragma unroll
        for (int j = 0; j < 16; ++j)
            whh[q][j] = Whh4[(q * Hd + l) * 16 + j];

    const float* xgl = xg + (size_t)b * Tsz * NG + l;
    float* hout = h1out + (size_t)b * Tsz * Hd + l;

    float c = 0.0f, hcur = 0.0f;
    hrow[l] = 0.0f;

    float gA0 = xgl[0], gA1 = xgl[64], gA2 = xgl[128], gA3 = xgl[192];
    float gB0 = xgl[NG + 0], gB1 = xgl[NG + 64];
    float gB2 = xgl[NG + 128], gB3 = xgl[NG + 192];

    for (int ci = 0; ci < NCH; ++ci) {
#pragma unroll
        for (int q = 0; q < 4; ++q)
#pragma unroll
            for (int j = 0; j < 16; ++j) PIN4(whh[q][j]);
#pragma unroll 1
        for (int ct = 0; ct < CHUNK; ct += 2) {
            const int t = ci * CHUNK + ct;
            REC_STEP(t,     gA0, gA1, gA2, gA3, hout[(size_t)t * Hd] = hcur);
            REC_STEP(t + 1, gB0, gB1, gB2, gB3, hout[(size_t)(t + 1) * Hd] = hcur);
        }
    }
}

// Layer-1 recurrence + fused FC (identical structure; no per-step store).
__global__ __launch_bounds__(64, 1)
void lstm_rec1_fc(const float4* __restrict__ Whh4,
                  const float* __restrict__ xg,
                  const float* __restrict__ fcW,
                  const float* __restrict__ fcb,
                  float* __restrict__ out)
{
    __shared__ __align__(16) float hrow[Hd];
    const int l = threadIdx.x;
    const int b = blockIdx.x;

    float4 whh[4][16];
#pragma unroll
    for (int q = 0; q < 4; ++q)
#pragma unroll
        for (int j = 0; j < 16; ++j)
            whh[q][j] = Whh4[(q * Hd + l) * 16 + j];

    const float* xgl = xg + (size_t)b * Tsz * NG + l;

    float c = 0.0f, hcur = 0.0f;
    hrow[l] = 0.0f;

    float gA0 = xgl[0], gA1 = xgl[64], gA2 = xgl[128], gA3 = xgl[192];
    float gB0 = xgl[NG + 0], gB1 = xgl[NG + 64];
    float gB2 = xgl[NG + 128], gB3 = xgl[NG + 192];

    for (int ci = 0; ci < NCH; ++ci) {
#pragma unroll
        for (int q = 0; q < 4; ++q)
#pragma unroll
            for (int j = 0; j < 16; ++j) PIN4(whh[q][j]);
#pragma unroll 1
        for (int ct = 0; ct < CHUNK; ct += 2) {
            const int t = ci * CHUNK + ct;
            REC_STEP(t,     gA0, gA1, gA2, gA3, );
            REC_STEP(t + 1, gB0, gB1, gB2, gB3, );
        }
    }
    // FC over the wave: lane l holds h2[b, T-1, l]
    float psum = hcur * fcW[l];
#pragma unroll
    for (int off = 32; off > 0; off >>= 1)
        psum += __shfl_down(psum, off);
    if (l == 0) out[b] = psum + fcb[0];
}

// ============================================================================
// FALLBACK PATH (R3 kernels, proven 746 us) — used if workspace too small.
// ============================================================================
__global__ __launch_bounds__(256, 2)
void lstm_layer0_fb(const float* __restrict__ x,
                    const float4* __restrict__ Wih4,
                    const float4* __restrict__ Whh4,
                    const float* __restrict__ bih,
                    const float* __restrict__ bhh,
                    float* __restrict__ h1out)
{
    __shared__ __align__(16) float xbuf[2][CHUNK * Fin];
    __shared__ __align__(16) float hcopy[4][Hd];
    __shared__ float glds[2][Hd * 5];

    const int tid  = threadIdx.x;
    const int lane = tid & 63;
    const int wv   = tid >> 6;
    const int wvu  = __builtin_amdgcn_readfirstlane(wv);
    const int b    = blockIdx.x;

    float4 wih[8];
#pragma unroll
    for (int q = 0; q < 8; ++q) wih[q] = Wih4[tid * 8 + q];
    float4 whh[16];
#pragma unroll
    for (int q = 0; q < 16; ++q) whh[q] = Whh4[tid * 16 + q];
    float bias = bih[tid] + bhh[tid];

    float c = 0.0f;
    hcopy[wv][lane] = 0.0f;

    const float4* xsrc = (const float4*)(x + (size_t)b * Tsz * Fin);
    ((float4*)xbuf[0])[tid] = xsrc[tid];
    float* hout = h1out + (size_t)b * Tsz * Hd + lane;
    __syncthreads();

    for (int ci = 0; ci < NCH; ++ci) {
        const int cur = ci & 1;
        if (ci + 1 < NCH)
            ((float4*)xbuf[cur ^ 1])[tid] = xsrc[(ci + 1) * (CHUNK * Fin / 4) + tid];
#pragma unroll
        for (int q = 0; q < 8; ++q)  PIN4(wih[q]);
#pragma unroll
        for (int q = 0; q < 16; ++q) PIN4(whh[q]);
#pragma unroll 1
        for (int ct = 0; ct < CHUNK; ct += 2) {
#pragma unroll
            for (int pp = 0; pp < 2; ++pp) {
                const float4* xrow = (const float4*)&xbuf[cur][(ct + pp) * Fin];
                const float4* hrw  = (const float4*)&hcopy[wv][0];
                v2f a0 = {bias, 0.0f}, a1 = {0.0f, 0.0f};
#pragma unroll
                for (int q = 0; q < 8; ++q) {
                    float4 xv = xrow[q];
                    v2f b0 = {xv.x, xv.y}, b1 = {xv.z, xv.w};
                    v2f w0 = {wih[q].x, wih[q].y}, w1 = {wih[q].z, wih[q].w};
                    a0 = __builtin_elementwise_fma(b0, w0, a0);
                    a1 = __builtin_elementwise_fma(b1, w1, a1);
                }
#pragma unroll
                for (int q = 0; q < 16; ++q) {
                    float4 hv = hrw[q];
                    v2f b0 = {hv.x, hv.y}, b1 = {hv.z, hv.w};
                    v2f w0 = {whh[q].x, whh[q].y}, w1 = {whh[q].z, whh[q].w};
                    a0 = __builtin_elementwise_fma(b0, w0, a0);
                    a1 = __builtin_elementwise_fma(b1, w1, a1);
                }
                float a = (a0.x + a0.y) + (a1.x + a1.y);
                if (wvu == 2) glds[pp][lane * 5 + wv] = ftanh(a);
                else          glds[pp][lane * 5 + wv] = fsig(a);
                __syncthreads();
                float gi = glds[pp][lane * 5 + 0];
                float gf = glds[pp][lane * 5 + 1];
                float gg = glds[pp][lane * 5 + 2];
                float go = glds[pp][lane * 5 + 3];
                c = fmaf(gf, c, gi * gg);
                float h = go * ftanh(c);
                hcopy[wv][lane] = h;
                if (wvu == 0)
                    hout[(size_t)(ci * CHUNK + ct + pp) * Hd] = h;
            }
        }
    }
}

__global__ __launch_bounds__(256, 2)
void lstm_layer1_fc_fb(const float* __restrict__ h1,
                       const float4* __restrict__ Wih4,
                       const float4* __restrict__ Whh4,
                       const float* __restrict__ bih,
                       const float* __restrict__ bhh,
                       const float* __restrict__ fcW,
                       const float* __restrict__ fcb,
                       float* __restrict__ out)
{
    __shared__ __align__(16) float xbuf[2][CHUNK * Hd];
    __shared__ __align__(16) float hcopy[4][Hd];
    __shared__ float glds[2][Hd * 5];

    const int tid  = threadIdx.x;
    const int lane = tid & 63;
    const int wv   = tid >> 6;
    const int wvu  = __builtin_amdgcn_readfirstlane(wv);
    const int b    = blockIdx.x;

    float4 wih[16];
#pragma unroll
    for (int q = 0; q < 16; ++q) wih[q] = Wih4[tid * 16 + q];
    float4 whh[16];
#pragma unroll
    for (int q = 0; q < 16; ++q) whh[q] = Whh4[tid * 16 + q];
    float bias = bih[tid] + bhh[tid];

    float c  = 0.0f;
    float hl = 0.0f;
    hcopy[wv][lane] = 0.0f;

    const float4* xsrc = (const float4*)(h1 + (size_t)b * Tsz * Hd);
    ((float4*)xbuf[0])[tid]       = xsrc[tid];
    ((float4*)xbuf[0])[tid + 256] = xsrc[tid + 256];
    __syncthreads();

    for (int ci = 0; ci < NCH; ++ci) {
        const int cur = ci & 1;
        if (ci + 1 < NCH) {
            ((float4*)xbuf[cur ^ 1])[tid]       = xsrc[(ci + 1) * (CHUNK * Hd / 4) + tid];
            ((float4*)xbuf[cur ^ 1])[tid + 256] = xsrc[(ci + 1) * (CHUNK * Hd / 4) + tid + 256];
        }
#pragma unroll
        for (int q = 0; q < 16; ++q) PIN4(wih[q]);
#pragma unroll
        for (int q = 0; q < 16; ++q) PIN4(whh[q]);
#pragma unroll 1
        for (int ct = 0; ct < CHUNK; ct += 2) {
#pragma unroll
            for (int pp = 0; pp < 2; ++pp) {
                const float4* xrow = (const float4*)&xbuf[cur][(ct + pp) * Hd];
                const float4* hrw  = (const float4*)&hcopy[wv][0];
                v2f a0 = {bias, 0.0f}, a1 = {0.0f, 0.0f};
#pragma unroll
                for (int q = 0; q < 16; ++q) {
                    float4 xv = xrow[q];
                    v2f b0 = {xv.x, xv.y}, b1 = {xv.z, xv.w};
                    v2f w0 = {wih[q].x, wih[q].y}, w1 = {wih[q].z, wih[q].w};
                    a0 = __builtin_elementwise_fma(b0, w0, a0);
                    a1 = __builtin_elementwise_fma(b1, w1, a1);
                }
#pragma unroll
                for (int q = 0; q < 16; ++q) {
                    float4 hv = hrw[q];
                    v2f b0 = {hv.x, hv.y}, b1 = {hv.z, hv.w};
                    v2f w0 = {whh[q].x, whh[q].y}, w1 = {whh[q].z, whh[q].w};
                    a0 = __builtin_elementwise_fma(b0, w0, a0);
                    a1 = __builtin_elementwise_fma(b1, w1, a1);
                }
                float a = (a0.x + a0.y) + (a1.x + a1.y);
                if (wvu == 2) glds[pp][lane * 5 + wv] = ftanh(a);
                else          glds[pp][lane * 5 + wv] = fsig(a);
                __syncthreads();
                float gi = glds[pp][lane * 5 + 0];
                float gf = glds[pp][lane * 5 + 1];
                float gg = glds[pp][lane * 5 + 2];
                float go = glds[pp][lane * 5 + 3];
                c  = fmaf(gf, c, gi * gg);
                hl = go * ftanh(c);
                hcopy[wv][lane] = hl;
            }
        }
    }
    if (wvu == 0) {
        float psum = hl * fcW[lane];
#pragma unroll
        for (int off = 32; off > 0; off >>= 1)
            psum += __shfl_down(psum, off);
        if (lane == 0) out[b] = psum + fcb[0];
    }
}

extern "C" void kernel_launch(void* const* d_in, const int* in_sizes, int n_in,
                              void* d_out, int out_size, void* d_ws, size_t ws_size,
                              hipStream_t stream)
{
    const float* x    = (const float*)d_in[0];
    const float* Wih0 = (const float*)d_in[1];
    const float* Whh0 = (const float*)d_in[2];
    const float* bih0 = (const float*)d_in[3];
    const float* bhh0 = (const float*)d_in[4];
    const float* Wih1 = (const float*)d_in[5];
    const float* Whh1 = (const float*)d_in[6];
    const float* bih1 = (const float*)d_in[7];
    const float* bhh1 = (const float*)d_in[8];
    const float* fcW  = (const float*)d_in[9];
    const float* fcb  = (const float*)d_in[10];
    float* out = (float*)d_out;

    const size_t h1_bytes = (size_t)Bsz * Tsz * Hd * sizeof(float);   //  67 MB
    const size_t xg_bytes = (size_t)NBT * NG * sizeof(float);         // 268 MB

    if (ws_size >= h1_bytes + xg_bytes) {
        float* h1 = (float*)d_ws;
        float* xg = (float*)((char*)d_ws + h1_bytes);
        // 1. xg0 = x·Wih0^T + biases  (streaming GEMM, all (b,t) parallel)
        xg_gemm<Fin><<<dim3(NBT / 64), dim3(256), 0, stream>>>(
            x, (const float4*)Wih0, bih0, bhh0, xg);
        // 2. layer-0 recurrence: barrier-free, 1 wave per batch row
        lstm_rec0<<<dim3(Bsz), dim3(64), 0, stream>>>(
            (const float4*)Whh0, xg, h1);
        // 3. xg1 = h1·Wih1^T + biases (reuses xg buffer)
        xg_gemm<Hd><<<dim3(NBT / 64), dim3(256), 0, stream>>>(
            h1, (const float4*)Wih1, bih1, bhh1, xg);
        // 4. layer-1 recurrence + fused FC
        lstm_rec1_fc<<<dim3(Bsz), dim3(64), 0, stream>>>(
            (const float4*)Whh1, xg, fcW, fcb, out);
    } else {
        float* h1 = (float*)d_ws;
        lstm_layer0_fb<<<dim3(Bsz), dim3(256), 0, stream>>>(
            x, (const float4*)Wih0, (const float4*)Whh0, bih0, bhh0, h1);
        lstm_layer1_fc_fb<<<dim3(Bsz), dim3(256), 0, stream>>>(
            h1, (const float4*)Wih1, (const float4*)Whh1, bih1, bhh1, fcW, fcb, out);
    }
}